// Round 12
// baseline (248.664 us; speedup 1.0000x reference)
//
#include <hip/hip_runtime.h>
#include <hip/hip_cooperative_groups.h>
#include <cstdint>

namespace cg = cooperative_groups;

typedef __bf16 bf16x8 __attribute__((ext_vector_type(8)));
typedef float f32x4 __attribute__((ext_vector_type(4)));
typedef unsigned short u16;

#define NROWS 4096
#define DIM 512
#define ZROWS 8192
#define DIMP 128     /* projected dims (Walsh coefficients 0..127) */
#define NTILES 64    /* 8192/128 */
#define NBLOCKS 2080 /* 64*65/2 upper-triangular 128x128 tile pairs */
#define CGRID 512    /* 2 blocks/CU — co-residency guaranteed for any VGPR<=256 */
#define THR 80.0f    /* certify-skip: d_proj>=80 => d_true>=~79 => sum < 1e-9 */

// =========================== shared device helpers ================================
__device__ __forceinline__ void fwht_row(const float* __restrict__ src, int l,
                                         float (&h)[8], float& nrm) {
    const float4 v0 = *(const float4*)(src + l * 8);
    const float4 v1 = *(const float4*)(src + l * 8 + 4);
    h[0] = v0.x; h[1] = v0.y; h[2] = v0.z; h[3] = v0.w;
    h[4] = v1.x; h[5] = v1.y; h[6] = v1.z; h[7] = v1.w;
    nrm = 0.f;
#pragma unroll
    for (int j = 0; j < 8; ++j) nrm += h[j] * h[j];
#pragma unroll
    for (int off = 32; off; off >>= 1) nrm += __shfl_xor(nrm, off);
#define BFLY(a, b) { float t = h[a]; h[a] = t + h[b]; h[b] = t - h[b]; }
    BFLY(0, 1) BFLY(2, 3) BFLY(4, 5) BFLY(6, 7)
    BFLY(0, 2) BFLY(1, 3) BFLY(4, 6) BFLY(5, 7)
    BFLY(0, 4) BFLY(1, 5) BFLY(2, 6) BFLY(3, 7)
#undef BFLY
#pragma unroll
    for (int m = 1; m <= 32; m <<= 1) {
#pragma unroll
        for (int j = 0; j < 8; ++j) {
            float p = __shfl_xor(h[j], m);
            h[j] = (l & m) ? (p - h[j]) : (h[j] + p);
        }
    }
}

// quantize coefs 0..127 (lanes 0..15) to bf16, accumulate pnorm partial
__device__ __forceinline__ void quant_row(float (&h)[8], int l, uint32_t (&pk)[4],
                                          float& s) {
    s = 0.f;
#pragma unroll
    for (int jj = 0; jj < 4; ++jj) {
        uint32_t b0 = __float_as_uint(h[2 * jj] * 0.04419417382f);
        uint32_t b1 = __float_as_uint(h[2 * jj + 1] * 0.04419417382f);
        uint32_t r0 = (b0 + 0x7fffu + ((b0 >> 16) & 1u)) >> 16;
        uint32_t r1 = (b1 + 0x7fffu + ((b1 >> 16) & 1u)) >> 16;
        pk[jj] = r0 | (r1 << 16);
        float fb0 = __uint_as_float(r0 << 16);
        float fb1 = __uint_as_float(r1 << 16);
        s += fb0 * fb0 + fb1 * fb1;
    }
    s = (l < 16) ? s : 0.f;
#pragma unroll
    for (int off = 32; off; off >>= 1) s += __shfl_xor(s, off);
}

// register-MFMA certify filter for one 128x128 tile pair; returns signed sum
__device__ __forceinline__ float tile_term(int bm, int bn, int wv, int l,
                                           const u16* __restrict__ Q,
                                           const float* __restrict__ pnorm,
                                           const float* __restrict__ lbl,
                                           const float* __restrict__ pred,
                                           const float* __restrict__ xnorm) {
    const int wm = wv >> 1, wn = wv & 1;
    const int rl = l & 15;
    const int kb = (l >> 4) * 16;
    const int rowA = bm * 128 + wm * 64;
    const int rowB = bn * 128 + wn * 64;
    const char* baseA = (const char*)Q + (size_t)(rowA + rl) * 256 + kb;
    const char* baseB = (const char*)Q + (size_t)(rowB + rl) * 256 + kb;

    f32x4 acc[4][4];
#pragma unroll
    for (int m = 0; m < 4; ++m)
#pragma unroll
        for (int n = 0; n < 4; ++n) acc[m][n] = (f32x4){0.f, 0.f, 0.f, 0.f};

    auto LD = [&](bf16x8 (&a)[4], bf16x8 (&b)[4], int kc) {
#pragma unroll
        for (int m = 0; m < 4; ++m) {
            a[m] = *(const bf16x8*)(baseA + m * 4096 + kc * 64);
            b[m] = *(const bf16x8*)(baseB + m * 4096 + kc * 64);
        }
    };
    auto MM = [&](bf16x8 (&a)[4], bf16x8 (&b)[4]) {
#pragma unroll
        for (int m = 0; m < 4; ++m)
#pragma unroll
            for (int n = 0; n < 4; ++n)
                acc[m][n] = __builtin_amdgcn_mfma_f32_16x16x32_bf16(a[m], b[n], acc[m][n], 0, 0, 0);
    };
    bf16x8 aE[4], bE[4], aO[4], bO[4];
    LD(aE, bE, 0);
    LD(aO, bO, 1); MM(aE, bE);
    LD(aE, bE, 2); MM(aO, bO);
    LD(aO, bO, 3); MM(aE, bE);
    MM(aO, bO);

    float pj[4];
    float4 piv[4];
#pragma unroll
    for (int n = 0; n < 4; ++n) pj[n] = pnorm[rowB + n * 16 + rl];
#pragma unroll
    for (int m = 0; m < 4; ++m)
        piv[m] = *(const float4*)(pnorm + rowA + m * 16 + (l >> 4) * 4);

    float tmin = 1e30f;  // min fragment distance (i==j excluded)
#pragma unroll
    for (int m = 0; m < 4; ++m)
#pragma unroll
        for (int n = 0; n < 4; ++n) {
            const int i0 = rowA + m * 16 + (l >> 4) * 4;
            const int j = rowB + n * 16 + rl;
            const int delta = j - i0;
            float d0 = (piv[m].x + pj[n]) - 2.f * acc[m][n][0];
            float d1 = (piv[m].y + pj[n]) - 2.f * acc[m][n][1];
            float d2 = (piv[m].z + pj[n]) - 2.f * acc[m][n][2];
            float d3 = (piv[m].w + pj[n]) - 2.f * acc[m][n][3];
            d0 = (delta == 0) ? 1e30f : d0;
            d1 = (delta == 1) ? 1e30f : d1;
            d2 = (delta == 2) ? 1e30f : d2;
            d3 = (delta == 3) ? 1e30f : d3;
            tmin = fminf(tmin, fminf(fminf(d0, d1), fminf(d2, d3)));
        }

    if (!__ballot(tmin < THR)) return 0.f;  // certified: all terms < e^-38

    float local = 0.f;  // provably-rare exact path (wave-cooperative f32 dot)
#pragma unroll
    for (int m = 0; m < 4; ++m)
#pragma unroll
        for (int n = 0; n < 4; ++n) {
            float d[4];
            d[0] = (piv[m].x + pj[n]) - 2.f * acc[m][n][0];
            d[1] = (piv[m].y + pj[n]) - 2.f * acc[m][n][1];
            d[2] = (piv[m].z + pj[n]) - 2.f * acc[m][n][2];
            d[3] = (piv[m].w + pj[n]) - 2.f * acc[m][n][3];
            const int i0 = rowA + m * 16 + (l >> 4) * 4;
            const int j = rowB + n * 16 + rl;
#pragma unroll
            for (int r = 0; r < 4; ++r) {
                unsigned long long bal = __ballot((d[r] < THR) && (i0 + r != j));
                while (bal) {
                    const int src = __ffsll((long long)bal) - 1;
                    bal &= bal - 1;
                    const int ii = __shfl(i0 + r, src);
                    const int jj = __shfl(j, src);
                    const float* ri = (ii < NROWS) ? lbl + (size_t)ii * DIM
                                                   : pred + (size_t)(ii - NROWS) * DIM;
                    const float* rj = (jj < NROWS) ? lbl + (size_t)jj * DIM
                                                   : pred + (size_t)(jj - NROWS) * DIM;
                    const float4 a0 = *(const float4*)(ri + l * 8);
                    const float4 a1 = *(const float4*)(ri + l * 8 + 4);
                    const float4 c0 = *(const float4*)(rj + l * 8);
                    const float4 c1 = *(const float4*)(rj + l * 8 + 4);
                    float p = a0.x * c0.x + a0.y * c0.y + a0.z * c0.z + a0.w * c0.w +
                              a1.x * c1.x + a1.y * c1.y + a1.z * c1.z + a1.w * c1.w;
#pragma unroll
                    for (int off = 32; off; off >>= 1) p += __shfl_xor(p, off);
                    if (l == src) {
                        float dt = xnorm[ii] + xnorm[jj] - 2.f * p;
                        local += exp2f(-0.72134752f * dt);
                    }
                }
            }
        }
    const float sgn = ((bm < 32) == (bn < 32)) ? 1.f : -1.f;
    return local * sgn * ((bm == bn) ? 1.f : 2.f);
}

// =========================== path 1: fused cooperative ============================
__global__ __launch_bounds__(256) void mmd_fused(const float* __restrict__ lbl,
                                                 const float* __restrict__ pred,
                                                 u16* __restrict__ Q,
                                                 float* __restrict__ xnorm,
                                                 float* __restrict__ pnorm,
                                                 float* __restrict__ partials,
                                                 float* __restrict__ out) {
    __shared__ float red[4];
    cg::grid_group grid = cg::this_grid();
    const int bid = (int)blockIdx.x;
    const int tid = threadIdx.x;
    const int wv = tid >> 6;
    const int l = tid & 63;

    // Phase A: FWHT projection + norms — 4 rows per wave (2048 waves total)
    const int W = bid * 4 + wv;
#pragma unroll
    for (int k = 0; k < 4; ++k) {
        const int row = W + k * 2048;
        const float* src = (row < NROWS) ? (lbl + (size_t)row * DIM)
                                         : (pred + (size_t)(row - NROWS) * DIM);
        float h[8], nrm, s;
        uint32_t pk[4];
        fwht_row(src, l, h, nrm);
        if (l == 0) xnorm[row] = nrm;
        quant_row(h, l, pk, s);
        if (l < 16) *(uint4*)(Q + (size_t)row * DIMP + l * 8)
            = make_uint4(pk[0], pk[1], pk[2], pk[3]);
        if (l == 0) pnorm[row] = s;
    }

    __threadfence();  // agent-scope release: L2 writeback -> cross-XCD visible
    grid.sync();

    // Phase B: certify filter, tiles strided by grid
    float grand = 0.f;
    for (int t = bid; t < NBLOCKS; t += CGRID) {
        int bm = 0, rem = t;
        while (rem >= NTILES - bm) { rem -= NTILES - bm; ++bm; }
        grand += tile_term(bm, bm + rem, wv, l, Q, pnorm, lbl, pred, xnorm);
    }
#pragma unroll
    for (int off = 32; off; off >>= 1) grand += __shfl_xor(grand, off);
    if (l == 0) red[wv] = grand;
    __syncthreads();
    if (tid == 0) partials[bid] = red[0] + red[1] + red[2] + red[3];

    __threadfence();
    grid.sync();

    // Phase C: block 0 final reduce
    if (bid == 0) {
        float s = 0.f;
        for (int i = tid; i < CGRID; i += 256) s += partials[i];
#pragma unroll
        for (int off = 32; off; off >>= 1) s += __shfl_xor(s, off);
        if (l == 0) red[wv] = s;
        __syncthreads();
        if (tid == 0)  // + 8192 = Z-diagonal (exp(0)=1, sign +1, exact)
            out[0] = (red[0] + red[1] + red[2] + red[3] + 8192.f) * (1.f / 16777216.f);
    }
}

// =========================== path 2: 3-kernel fallback (round-9, proven) ==========
__global__ __launch_bounds__(256) void prep_kernel(const float* __restrict__ lbl,
                                                   const float* __restrict__ pred,
                                                   u16* __restrict__ Q,
                                                   float* __restrict__ xnorm,
                                                   float* __restrict__ pnorm) {
    const int w = threadIdx.x >> 6;
    const int l = threadIdx.x & 63;
    const int row = blockIdx.x * 4 + w;
    const float* src = (row < NROWS) ? (lbl + (size_t)row * DIM)
                                     : (pred + (size_t)(row - NROWS) * DIM);
    float h[8], nrm, s;
    uint32_t pk[4];
    fwht_row(src, l, h, nrm);
    if (l == 0) xnorm[row] = nrm;
    quant_row(h, l, pk, s);
    if (l < 16) *(uint4*)(Q + (size_t)row * DIMP + l * 8)
        = make_uint4(pk[0], pk[1], pk[2], pk[3]);
    if (l == 0) pnorm[row] = s;
}

__global__ __launch_bounds__(256) void mmd_filter_kernel(const u16* __restrict__ Q,
                                                         const float* __restrict__ pnorm,
                                                         const float* __restrict__ lbl,
                                                         const float* __restrict__ pred,
                                                         const float* __restrict__ xnorm,
                                                         float* __restrict__ partials) {
    __shared__ float red[4];
    const int bid = (int)blockIdx.x;
    int bm = 0, rem = bid;
    while (rem >= NTILES - bm) { rem -= NTILES - bm; ++bm; }
    const int tid = threadIdx.x;
    float grand = tile_term(bm, bm + rem, tid >> 6, tid & 63, Q, pnorm, lbl, pred, xnorm);
#pragma unroll
    for (int off = 32; off; off >>= 1) grand += __shfl_xor(grand, off);
    if ((tid & 63) == 0) red[tid >> 6] = grand;
    __syncthreads();
    if (tid == 0) partials[bid] = red[0] + red[1] + red[2] + red[3];
}

__global__ __launch_bounds__(256) void reduce_kernel(const float* __restrict__ partials,
                                                     float* __restrict__ out, int n) {
    __shared__ float red[4];
    float s = 0.f;
    for (int i = threadIdx.x; i < n; i += 256) s += partials[i];
#pragma unroll
    for (int off = 32; off; off >>= 1) s += __shfl_xor(s, off);
    if ((threadIdx.x & 63) == 0) red[threadIdx.x >> 6] = s;
    __syncthreads();
    if (threadIdx.x == 0)
        out[0] = (red[0] + red[1] + red[2] + red[3] + 8192.f) * (1.f / 16777216.f);
}

extern "C" void kernel_launch(void* const* d_in, const int* in_sizes, int n_in,
                              void* d_out, int out_size, void* d_ws, size_t ws_size,
                              hipStream_t stream) {
    const float* lbl = (const float*)d_in[0];
    const float* pred = (const float*)d_in[1];
    u16* Q = (u16*)d_ws;                                              // 2 MiB
    float* xnorm = (float*)((char*)d_ws + (size_t)ZROWS * DIMP * 2);  // 32 KiB
    float* pnorm = xnorm + ZROWS;                                     // 32 KiB
    float* partials = pnorm + ZROWS;                                  // 8.3 KiB
    float* out = (float*)d_out;

    void* args[] = {&lbl, &pred, &Q, &xnorm, &pnorm, &partials, &out};
    hipError_t err = hipLaunchCooperativeKernel((const void*)mmd_fused, dim3(CGRID),
                                                dim3(256), args, 0, stream);
    if (err != hipSuccess) {
        (void)hipGetLastError();  // clear sticky error; take the proven 3-kernel path
        prep_kernel<<<ZROWS / 4, 256, 0, stream>>>(lbl, pred, Q, xnorm, pnorm);
        mmd_filter_kernel<<<NBLOCKS, 256, 0, stream>>>(Q, pnorm, lbl, pred, xnorm, partials);
        reduce_kernel<<<1, 256, 0, stream>>>(partials, out, NBLOCKS);
    }
}

// Round 13
// 40.466 us; speedup vs baseline: 6.1450x; 6.1450x over previous
//
#include <hip/hip_runtime.h>
#include <cstdint>

typedef __bf16 bf16x8 __attribute__((ext_vector_type(8)));
typedef float f32x4 __attribute__((ext_vector_type(4)));
typedef unsigned short u16;

#define NROWS 4096
#define DIM 512
#define ZROWS 8192
#define DIMP 128     /* projected dims (Walsh coefficients 0..127) */
#define NTILES 64    /* 8192/128 */
#define NBLOCKS 2080 /* 64*65/2 upper-triangular 128x128 tile pairs */
#define CHUNK 260    /* NBLOCKS/8 — bijective XCD swizzle */
#define THR 80.0f    /* certify-skip: d_proj>=80 => d_true>=~79 => sum < 1e-9 */

// ---------------- kernel 1: FWHT projection + norms, FRAGMENT-ORDERED Q ----------
// FWHT over 512 elems (exact Sylvester WHT; rows of H/sqrt(512) orthonormal =>
// Parseval: d_proj <= d_true). Q is stored in MFMA-FRAGMENT ORDER so the filter's
// loads are wave-contiguous (lane l reads base + l*16 — 8 cache lines/instr
// instead of 32 for the row-major layout; r9-r12's ~45us floor matches the
// per-CU L1/TA line-gather rate, all throughput counters idle).
// 16-B unit (row, l<16) -> Qf[(row>>4)*256 + (l>>2)*64 + (l&3)*16 + (row&15)].
__global__ __launch_bounds__(256) void prep_kernel(const float* __restrict__ lbl,
                                                   const float* __restrict__ pred,
                                                   u16* __restrict__ Qf,
                                                   float* __restrict__ xnorm,
                                                   float* __restrict__ pnorm) {
    const int w = threadIdx.x >> 6;
    const int l = threadIdx.x & 63;
    const int row = blockIdx.x * 4 + w;
    const float* src = (row < NROWS) ? (lbl + (size_t)row * DIM)
                                     : (pred + (size_t)(row - NROWS) * DIM);
    const float4 v0 = *(const float4*)(src + l * 8);
    const float4 v1 = *(const float4*)(src + l * 8 + 4);
    float h[8] = {v0.x, v0.y, v0.z, v0.w, v1.x, v1.y, v1.z, v1.w};

    float nrm = 0.f;  // exact f32 norm of the ORIGINAL row (fallback uses it)
#pragma unroll
    for (int j = 0; j < 8; ++j) nrm += h[j] * h[j];
#pragma unroll
    for (int off = 32; off; off >>= 1) nrm += __shfl_xor(nrm, off);
    if (l == 0) xnorm[row] = nrm;

#define BFLY(a, b) { float t = h[a]; h[a] = t + h[b]; h[b] = t - h[b]; }
    BFLY(0, 1) BFLY(2, 3) BFLY(4, 5) BFLY(6, 7)
    BFLY(0, 2) BFLY(1, 3) BFLY(4, 6) BFLY(5, 7)
    BFLY(0, 4) BFLY(1, 5) BFLY(2, 6) BFLY(3, 7)
#undef BFLY
#pragma unroll
    for (int m = 1; m <= 32; m <<= 1) {
#pragma unroll
        for (int j = 0; j < 8; ++j) {
            float p = __shfl_xor(h[j], m);
            h[j] = (l & m) ? (p - h[j]) : (h[j] + p);
        }
    }
    // quantize q = h/sqrt(512) to bf16 (RNE); pnorm from bf16-rounded values
    float s = 0.f;
    uint32_t pk[4];
#pragma unroll
    for (int jj = 0; jj < 4; ++jj) {
        uint32_t b0 = __float_as_uint(h[2 * jj] * 0.04419417382f);
        uint32_t b1 = __float_as_uint(h[2 * jj + 1] * 0.04419417382f);
        uint32_t r0 = (b0 + 0x7fffu + ((b0 >> 16) & 1u)) >> 16;
        uint32_t r1 = (b1 + 0x7fffu + ((b1 >> 16) & 1u)) >> 16;
        pk[jj] = r0 | (r1 << 16);
        float fb0 = __uint_as_float(r0 << 16);
        float fb1 = __uint_as_float(r1 << 16);
        s += fb0 * fb0 + fb1 * fb1;
    }
    if (l < 16) {
        const size_t unit = (size_t)(row >> 4) * 256 + (l >> 2) * 64 + (l & 3) * 16 + (row & 15);
        *((uint4*)Qf + unit) = make_uint4(pk[0], pk[1], pk[2], pk[3]);
    }
    s = (l < 16) ? s : 0.f;
#pragma unroll
    for (int off = 32; off; off >>= 1) s += __shfl_xor(s, off);
    if (l == 0) pnorm[row] = s;
}

// ---------------- kernel 2: barrier-free register-MFMA filter, coalesced ---------
// r9 body; fragment loads are now contiguous 1-KB wave-loads from Qf.
__global__ __launch_bounds__(256) void mmd_filter_kernel(const u16* __restrict__ Qf,
                                                         const float* __restrict__ pnorm,
                                                         const float* __restrict__ lbl,
                                                         const float* __restrict__ pred,
                                                         const float* __restrict__ xnorm,
                                                         float* __restrict__ partials) {
    __shared__ float red[4];

    const int bid0 = (int)blockIdx.x;
    const int bid = (bid0 & 7) * CHUNK + (bid0 >> 3);  // XCD-contiguous ranges
    int bm = 0, rem = bid;
    while (rem >= NTILES - bm) { rem -= NTILES - bm; ++bm; }
    const int bn = bm + rem;

    const int tid = threadIdx.x;
    const int wv = tid >> 6;
    const int l = tid & 63;
    const int wm = wv >> 1, wn = wv & 1;

    const int rowA = bm * 128 + wm * 64;   // wave's A-row block (64 rows)
    const int rowB = bn * 128 + wn * 64;   // wave's B-row block (64 rows)
    const int rl = l & 15;

    // fragment-ordered bases: block16 stride 4096 B, chunk stride 1024 B, lane*16
    const char* baseA = (const char*)Qf + (size_t)(rowA >> 4) * 4096 + (size_t)l * 16;
    const char* baseB = (const char*)Qf + (size_t)(rowB >> 4) * 4096 + (size_t)l * 16;

    f32x4 acc[4][4];
#pragma unroll
    for (int m = 0; m < 4; ++m)
#pragma unroll
        for (int n = 0; n < 4; ++n) acc[m][n] = (f32x4){0.f, 0.f, 0.f, 0.f};

    auto LD = [&](bf16x8 (&a)[4], bf16x8 (&b)[4], int kc) {
#pragma unroll
        for (int m = 0; m < 4; ++m) {
            a[m] = *(const bf16x8*)(baseA + m * 4096 + kc * 1024);
            b[m] = *(const bf16x8*)(baseB + m * 4096 + kc * 1024);
        }
    };
    auto MM = [&](bf16x8 (&a)[4], bf16x8 (&b)[4]) {
#pragma unroll
        for (int m = 0; m < 4; ++m)
#pragma unroll
            for (int n = 0; n < 4; ++n)
                acc[m][n] = __builtin_amdgcn_mfma_f32_16x16x32_bf16(a[m], b[n], acc[m][n], 0, 0, 0);
    };

    // K=128 in 4 chunks, even/odd register double-buffer (static names, rule #20)
    bf16x8 aE[4], bE[4], aO[4], bO[4];
    LD(aE, bE, 0);
    LD(aO, bO, 1); MM(aE, bE);
    LD(aE, bE, 2); MM(aO, bO);
    LD(aO, bO, 3); MM(aE, bE);
    MM(aO, bO);

    // ---- epilogue: certify-skip via d_proj; rare exact fallback -------------------
    float pj[4];
    float4 piv[4];
#pragma unroll
    for (int n = 0; n < 4; ++n) pj[n] = pnorm[rowB + n * 16 + rl];
#pragma unroll
    for (int m = 0; m < 4; ++m)
        piv[m] = *(const float4*)(pnorm + rowA + m * 16 + (l >> 4) * 4);

    float tmin = 1e30f;  // min over the 64 fragment distances (i==j excluded)
#pragma unroll
    for (int m = 0; m < 4; ++m)
#pragma unroll
        for (int n = 0; n < 4; ++n) {
            const int i0 = rowA + m * 16 + (l >> 4) * 4;
            const int j = rowB + n * 16 + rl;
            const int delta = j - i0;  // i==j iff delta==r
            float d0 = (piv[m].x + pj[n]) - 2.f * acc[m][n][0];
            float d1 = (piv[m].y + pj[n]) - 2.f * acc[m][n][1];
            float d2 = (piv[m].z + pj[n]) - 2.f * acc[m][n][2];
            float d3 = (piv[m].w + pj[n]) - 2.f * acc[m][n][3];
            d0 = (delta == 0) ? 1e30f : d0;
            d1 = (delta == 1) ? 1e30f : d1;
            d2 = (delta == 2) ? 1e30f : d2;
            d3 = (delta == 3) ? 1e30f : d3;
            tmin = fminf(tmin, fminf(fminf(d0, d1), fminf(d2, d3)));
        }

    float grand = 0.f;
    if (__ballot(tmin < THR)) {  // ≈never taken (certified); wave-uniform branch
        float local = 0.f;
#pragma unroll
        for (int m = 0; m < 4; ++m)
#pragma unroll
            for (int n = 0; n < 4; ++n) {
                float d[4];
                d[0] = (piv[m].x + pj[n]) - 2.f * acc[m][n][0];
                d[1] = (piv[m].y + pj[n]) - 2.f * acc[m][n][1];
                d[2] = (piv[m].z + pj[n]) - 2.f * acc[m][n][2];
                d[3] = (piv[m].w + pj[n]) - 2.f * acc[m][n][3];
                const int i0 = rowA + m * 16 + (l >> 4) * 4;
                const int j = rowB + n * 16 + rl;
#pragma unroll
                for (int r = 0; r < 4; ++r) {
                    unsigned long long bal = __ballot((d[r] < THR) && (i0 + r != j));
                    while (bal) {  // wave-cooperative exact f32 term
                        const int src = __ffsll((long long)bal) - 1;
                        bal &= bal - 1;
                        const int ii = __shfl(i0 + r, src);
                        const int jj = __shfl(j, src);
                        const float* ri = (ii < NROWS) ? lbl + (size_t)ii * DIM
                                                       : pred + (size_t)(ii - NROWS) * DIM;
                        const float* rj = (jj < NROWS) ? lbl + (size_t)jj * DIM
                                                       : pred + (size_t)(jj - NROWS) * DIM;
                        const float4 a0 = *(const float4*)(ri + l * 8);
                        const float4 a1 = *(const float4*)(ri + l * 8 + 4);
                        const float4 c0 = *(const float4*)(rj + l * 8);
                        const float4 c1 = *(const float4*)(rj + l * 8 + 4);
                        float p = a0.x * c0.x + a0.y * c0.y + a0.z * c0.z + a0.w * c0.w +
                                  a1.x * c1.x + a1.y * c1.y + a1.z * c1.z + a1.w * c1.w;
#pragma unroll
                        for (int off = 32; off; off >>= 1) p += __shfl_xor(p, off);
                        if (l == src) {
                            float dt = xnorm[ii] + xnorm[jj] - 2.f * p;
                            local += exp2f(-0.72134752f * dt);
                        }
                    }
                }
            }
        const float sgn = ((bm < 32) == (bn < 32)) ? 1.f : -1.f;
        grand = local * sgn * ((bm == bn) ? 1.f : 2.f);
    }

    // ---- block reduce (the only synchronization in the kernel) ----
#pragma unroll
    for (int off = 32; off; off >>= 1) grand += __shfl_xor(grand, off);
    if (l == 0) red[wv] = grand;
    __syncthreads();
    if (tid == 0) partials[bid] = red[0] + red[1] + red[2] + red[3];
}

// ---------------- kernel 3: deterministic final reduce ---------------------------
__global__ __launch_bounds__(256) void reduce_kernel(const float* __restrict__ partials,
                                                     float* __restrict__ out, int n) {
    __shared__ float red[4];
    float s = 0.f;
    for (int i = threadIdx.x; i < n; i += 256) s += partials[i];
#pragma unroll
    for (int off = 32; off; off >>= 1) s += __shfl_xor(s, off);
    if ((threadIdx.x & 63) == 0) red[threadIdx.x >> 6] = s;
    __syncthreads();
    if (threadIdx.x == 0)  // + 8192 = the Z-diagonal (exp(0)=1, sign +1, exact)
        out[0] = (red[0] + red[1] + red[2] + red[3] + 8192.f) * (1.f / 16777216.f);
}

extern "C" void kernel_launch(void* const* d_in, const int* in_sizes, int n_in,
                              void* d_out, int out_size, void* d_ws, size_t ws_size,
                              hipStream_t stream) {
    const float* lbl = (const float*)d_in[0];
    const float* pred = (const float*)d_in[1];
    u16* Qf = (u16*)d_ws;                                             // 2 MiB
    float* xnorm = (float*)((char*)d_ws + (size_t)ZROWS * DIMP * 2);  // 32 KiB
    float* pnorm = xnorm + ZROWS;                                     // 32 KiB
    float* partials = pnorm + ZROWS;                                  // 8.3 KiB

    prep_kernel<<<ZROWS / 4, 256, 0, stream>>>(lbl, pred, Qf, xnorm, pnorm);
    mmd_filter_kernel<<<NBLOCKS, 256, 0, stream>>>(Qf, pnorm, lbl, pred, xnorm, partials);
    reduce_kernel<<<1, 256, 0, stream>>>(partials, (float*)d_out, NBLOCKS);
}

// Round 14
// 37.345 us; speedup vs baseline: 6.6586x; 1.0836x over previous
//
#include <hip/hip_runtime.h>
#include <cstdint>

typedef __bf16 bf16x8 __attribute__((ext_vector_type(8)));
typedef float f32x4 __attribute__((ext_vector_type(4)));
typedef unsigned short u16;

#define NROWS 4096
#define DIM 512
#define ZROWS 8192
#define DIMP 128     /* projected dims (Walsh coefficients 0..127) */
#define NTILES 64    /* 8192/128 */
#define NBLOCKS 2080 /* 64*65/2 upper-triangular 128x128 tile pairs */
#define GRID2 520    /* 2080/4 — each block walks 4 consecutive triangle ids */
#define THR 80.0f    /* certify-skip: d_proj>=80 => d_true>=~79 => sum < 1e-9 */

// ---------------- kernel 1: FWHT projection + norms, FRAGMENT-ORDERED Q ----------
// (r13, unchanged — broke the gather floor). Q stored in MFMA-fragment order:
// 16-B unit (row, l<16) -> Qf[(row>>4)*256 + (l>>2)*64 + (l&3)*16 + (row&15)],
// so filter lane L reads base + L*16 (fully coalesced 1-KB wave-loads).
__global__ __launch_bounds__(256) void prep_kernel(const float* __restrict__ lbl,
                                                   const float* __restrict__ pred,
                                                   u16* __restrict__ Qf,
                                                   float* __restrict__ xnorm,
                                                   float* __restrict__ pnorm) {
    const int w = threadIdx.x >> 6;
    const int l = threadIdx.x & 63;
    const int row = blockIdx.x * 4 + w;
    const float* src = (row < NROWS) ? (lbl + (size_t)row * DIM)
                                     : (pred + (size_t)(row - NROWS) * DIM);
    const float4 v0 = *(const float4*)(src + l * 8);
    const float4 v1 = *(const float4*)(src + l * 8 + 4);
    float h[8] = {v0.x, v0.y, v0.z, v0.w, v1.x, v1.y, v1.z, v1.w};

    float nrm = 0.f;  // exact f32 norm of the ORIGINAL row (fallback uses it)
#pragma unroll
    for (int j = 0; j < 8; ++j) nrm += h[j] * h[j];
#pragma unroll
    for (int off = 32; off; off >>= 1) nrm += __shfl_xor(nrm, off);
    if (l == 0) xnorm[row] = nrm;

#define BFLY(a, b) { float t = h[a]; h[a] = t + h[b]; h[b] = t - h[b]; }
    BFLY(0, 1) BFLY(2, 3) BFLY(4, 5) BFLY(6, 7)
    BFLY(0, 2) BFLY(1, 3) BFLY(4, 6) BFLY(5, 7)
    BFLY(0, 4) BFLY(1, 5) BFLY(2, 6) BFLY(3, 7)
#undef BFLY
#pragma unroll
    for (int m = 1; m <= 32; m <<= 1) {
#pragma unroll
        for (int j = 0; j < 8; ++j) {
            float p = __shfl_xor(h[j], m);
            h[j] = (l & m) ? (p - h[j]) : (h[j] + p);
        }
    }
    float s = 0.f;
    uint32_t pk[4];
#pragma unroll
    for (int jj = 0; jj < 4; ++jj) {
        uint32_t b0 = __float_as_uint(h[2 * jj] * 0.04419417382f);
        uint32_t b1 = __float_as_uint(h[2 * jj + 1] * 0.04419417382f);
        uint32_t r0 = (b0 + 0x7fffu + ((b0 >> 16) & 1u)) >> 16;
        uint32_t r1 = (b1 + 0x7fffu + ((b1 >> 16) & 1u)) >> 16;
        pk[jj] = r0 | (r1 << 16);
        float fb0 = __uint_as_float(r0 << 16);
        float fb1 = __uint_as_float(r1 << 16);
        s += fb0 * fb0 + fb1 * fb1;
    }
    if (l < 16) {
        const size_t unit = (size_t)(row >> 4) * 256 + (l >> 2) * 64 + (l & 3) * 16 + (row & 15);
        *((uint4*)Qf + unit) = make_uint4(pk[0], pk[1], pk[2], pk[3]);
    }
    s = (l < 16) ? s : 0.f;
#pragma unroll
    for (int off = 32; off; off >>= 1) s += __shfl_xor(s, off);
    if (l == 0) pnorm[row] = s;
}

// ---------------- kernel 2: persistent 4-tile register-MFMA filter ----------------
// 520 blocks; block walks 4 CONSECUTIVE triangle ids (A-rows L2/L1-hot). Cross-
// tile prefetch: next tile's chunk-0 loads issue into the freed even registers
// BEFORE the current epilogue -> its L2 latency hides under ~400 cyc of epilogue.
__global__ __launch_bounds__(256) void mmd_filter_kernel(const u16* __restrict__ Qf,
                                                         const float* __restrict__ pnorm,
                                                         const float* __restrict__ lbl,
                                                         const float* __restrict__ pred,
                                                         const float* __restrict__ xnorm,
                                                         float* __restrict__ partials) {
    __shared__ float red[4];

    const int bid0 = (int)blockIdx.x;
    const int phys = (bid0 & 7) * (GRID2 / 8) + (bid0 >> 3);  // XCD-contiguous
    const int tid = threadIdx.x;
    const int wv = tid >> 6;
    const int l = tid & 63;
    const int wm = wv >> 1, wn = wv & 1;
    const int rl = l & 15;

    // decode first triangle index
    int bm = 0, rem = phys * 4;
    while (rem >= NTILES - bm) { rem -= NTILES - bm; ++bm; }

    auto baseof = [&](int rowblk) {
        return (const char*)Qf + (size_t)(rowblk >> 4) * 4096 + (size_t)l * 16;
    };

    f32x4 acc[4][4];
#pragma unroll
    for (int m = 0; m < 4; ++m)
#pragma unroll
        for (int n = 0; n < 4; ++n) acc[m][n] = (f32x4){0.f, 0.f, 0.f, 0.f};

    bf16x8 aE[4], bE[4], aO[4], bO[4];
    const char* bA = baseof(bm * 128 + wm * 64);
    const char* bB = baseof((bm + rem) * 128 + wn * 64);

#define LDX(a, b, kc, pA, pB)                                    \
    {                                                            \
        _Pragma("unroll") for (int m = 0; m < 4; ++m) {          \
            a[m] = *(const bf16x8*)((pA) + m * 4096 + (kc) * 1024); \
            b[m] = *(const bf16x8*)((pB) + m * 4096 + (kc) * 1024); \
        }                                                        \
    }
#define MMX(a, b)                                                \
    {                                                            \
        _Pragma("unroll") for (int m = 0; m < 4; ++m)            \
            _Pragma("unroll") for (int n = 0; n < 4; ++n)        \
                acc[m][n] = __builtin_amdgcn_mfma_f32_16x16x32_bf16(a[m], b[n], acc[m][n], 0, 0, 0); \
    }

    LDX(aE, bE, 0, bA, bB);
    float grand = 0.f;

#pragma unroll 1
    for (int k = 0; k < 4; ++k) {
        const int bn = bm + rem;
        const int rowA = bm * 128 + wm * 64;
        const int rowB = bn * 128 + wn * 64;

        LDX(aO, bO, 1, bA, bB); MMX(aE, bE);
        LDX(aE, bE, 2, bA, bB); MMX(aO, bO);
        LDX(aO, bO, 3, bA, bB); MMX(aE, bE);

        // advance to next tile; prefetch its chunk 0 into the freed even regs
        int bm2 = bm, rem2 = rem + 1;
        if (rem2 >= NTILES - bm2) { rem2 = 0; ++bm2; }
        if (k < 3) {
            bA = baseof(bm2 * 128 + wm * 64);
            bB = baseof((bm2 + rem2) * 128 + wn * 64);
            LDX(aE, bE, 0, bA, bB);
        }
        MMX(aO, bO);

        // ---- epilogue (register-only; certify-skip + rare exact fallback) ----
        float pj[4];
        float4 piv[4];
#pragma unroll
        for (int n = 0; n < 4; ++n) pj[n] = pnorm[rowB + n * 16 + rl];
#pragma unroll
        for (int m = 0; m < 4; ++m)
            piv[m] = *(const float4*)(pnorm + rowA + m * 16 + (l >> 4) * 4);

        float tmin = 1e30f;  // min fragment distance (i==j excluded)
#pragma unroll
        for (int m = 0; m < 4; ++m)
#pragma unroll
            for (int n = 0; n < 4; ++n) {
                const int i0 = rowA + m * 16 + (l >> 4) * 4;
                const int j = rowB + n * 16 + rl;
                const int delta = j - i0;
                float d0 = (piv[m].x + pj[n]) - 2.f * acc[m][n][0];
                float d1 = (piv[m].y + pj[n]) - 2.f * acc[m][n][1];
                float d2 = (piv[m].z + pj[n]) - 2.f * acc[m][n][2];
                float d3 = (piv[m].w + pj[n]) - 2.f * acc[m][n][3];
                d0 = (delta == 0) ? 1e30f : d0;
                d1 = (delta == 1) ? 1e30f : d1;
                d2 = (delta == 2) ? 1e30f : d2;
                d3 = (delta == 3) ? 1e30f : d3;
                tmin = fminf(tmin, fminf(fminf(d0, d1), fminf(d2, d3)));
            }

        if (__ballot(tmin < THR)) {  // ≈never taken (certified); wave-uniform
            float local = 0.f;
#pragma unroll
            for (int m = 0; m < 4; ++m)
#pragma unroll
                for (int n = 0; n < 4; ++n) {
                    float d[4];
                    d[0] = (piv[m].x + pj[n]) - 2.f * acc[m][n][0];
                    d[1] = (piv[m].y + pj[n]) - 2.f * acc[m][n][1];
                    d[2] = (piv[m].z + pj[n]) - 2.f * acc[m][n][2];
                    d[3] = (piv[m].w + pj[n]) - 2.f * acc[m][n][3];
                    const int i0 = rowA + m * 16 + (l >> 4) * 4;
                    const int j = rowB + n * 16 + rl;
#pragma unroll
                    for (int r = 0; r < 4; ++r) {
                        unsigned long long bal = __ballot((d[r] < THR) && (i0 + r != j));
                        while (bal) {  // wave-cooperative exact f32 term
                            const int src = __ffsll((long long)bal) - 1;
                            bal &= bal - 1;
                            const int ii = __shfl(i0 + r, src);
                            const int jj = __shfl(j, src);
                            const float* ri = (ii < NROWS) ? lbl + (size_t)ii * DIM
                                                           : pred + (size_t)(ii - NROWS) * DIM;
                            const float* rj = (jj < NROWS) ? lbl + (size_t)jj * DIM
                                                           : pred + (size_t)(jj - NROWS) * DIM;
                            const float4 a0 = *(const float4*)(ri + l * 8);
                            const float4 a1 = *(const float4*)(ri + l * 8 + 4);
                            const float4 c0 = *(const float4*)(rj + l * 8);
                            const float4 c1 = *(const float4*)(rj + l * 8 + 4);
                            float p = a0.x * c0.x + a0.y * c0.y + a0.z * c0.z + a0.w * c0.w +
                                      a1.x * c1.x + a1.y * c1.y + a1.z * c1.z + a1.w * c1.w;
#pragma unroll
                            for (int off = 32; off; off >>= 1) p += __shfl_xor(p, off);
                            if (l == src) {
                                float dt = xnorm[ii] + xnorm[jj] - 2.f * p;
                                local += exp2f(-0.72134752f * dt);
                            }
                        }
                    }
                }
            const float sgn = ((bm < 32) == (bn < 32)) ? 1.f : -1.f;
            grand += local * sgn * ((bm == bn) ? 1.f : 2.f);
        }
#pragma unroll
        for (int m = 0; m < 4; ++m)
#pragma unroll
            for (int n = 0; n < 4; ++n) acc[m][n] = (f32x4){0.f, 0.f, 0.f, 0.f};
        bm = bm2; rem = rem2;
    }
#undef LDX
#undef MMX

    // ---- block reduce ----
#pragma unroll
    for (int off = 32; off; off >>= 1) grand += __shfl_xor(grand, off);
    if (l == 0) red[wv] = grand;
    __syncthreads();
    if (tid == 0) partials[phys] = red[0] + red[1] + red[2] + red[3];
}

// ---------------- kernel 3: deterministic final reduce ---------------------------
__global__ __launch_bounds__(256) void reduce_kernel(const float* __restrict__ partials,
                                                     float* __restrict__ out, int n) {
    __shared__ float red[4];
    float s = 0.f;
    for (int i = threadIdx.x; i < n; i += 256) s += partials[i];
#pragma unroll
    for (int off = 32; off; off >>= 1) s += __shfl_xor(s, off);
    if ((threadIdx.x & 63) == 0) red[threadIdx.x >> 6] = s;
    __syncthreads();
    if (threadIdx.x == 0)  // + 8192 = the Z-diagonal (exp(0)=1, sign +1, exact)
        out[0] = (red[0] + red[1] + red[2] + red[3] + 8192.f) * (1.f / 16777216.f);
}

extern "C" void kernel_launch(void* const* d_in, const int* in_sizes, int n_in,
                              void* d_out, int out_size, void* d_ws, size_t ws_size,
                              hipStream_t stream) {
    const float* lbl = (const float*)d_in[0];
    const float* pred = (const float*)d_in[1];
    u16* Qf = (u16*)d_ws;                                             // 2 MiB
    float* xnorm = (float*)((char*)d_ws + (size_t)ZROWS * DIMP * 2);  // 32 KiB
    float* pnorm = xnorm + ZROWS;                                     // 32 KiB
    float* partials = pnorm + ZROWS;                                  // 2.1 KiB

    prep_kernel<<<ZROWS / 4, 256, 0, stream>>>(lbl, pred, Qf, xnorm, pnorm);
    mmd_filter_kernel<<<GRID2, 256, 0, stream>>>(Qf, pnorm, lbl, pred, xnorm, partials);
    reduce_kernel<<<1, 256, 0, stream>>>(partials, (float*)d_out, GRID2);
}

// Round 15
// 36.855 us; speedup vs baseline: 6.7470x; 1.0133x over previous
//
#include <hip/hip_runtime.h>
#include <cstdint>

typedef __bf16 bf16x8 __attribute__((ext_vector_type(8)));
typedef float f32x4 __attribute__((ext_vector_type(4)));
typedef unsigned short u16;

#define NROWS 4096
#define DIM 512
#define ZROWS 8192
#define DIMP 128     /* projected dims (Walsh coefficients 0..127) */
#define NTILES 64    /* 8192/128 */
#define NBLOCKS 2080 /* 64*65/2 upper-triangular 128x128 tile pairs */
#define GRID3 1040   /* 2080/2 — 2 tiles/block: 4 blocks/CU resident, 4 waves/SIMD */
#define THR 80.0f    /* certify-skip: d_proj>=80 => d_true>=~79 => sum < 1e-9 */

// ---------------- kernel 1: FWHT projection + norms, FRAGMENT-ORDERED Q ----------
// (r13, unchanged — broke the gather floor). Q stored in MFMA-fragment order:
// 16-B unit (row, l<16) -> Qf[(row>>4)*256 + (l>>2)*64 + (l&3)*16 + (row&15)],
// so filter lane L reads base + L*16 (fully coalesced 1-KB wave-loads).
__global__ __launch_bounds__(256) void prep_kernel(const float* __restrict__ lbl,
                                                   const float* __restrict__ pred,
                                                   u16* __restrict__ Qf,
                                                   float* __restrict__ xnorm,
                                                   float* __restrict__ pnorm) {
    const int w = threadIdx.x >> 6;
    const int l = threadIdx.x & 63;
    const int row = blockIdx.x * 4 + w;
    const float* src = (row < NROWS) ? (lbl + (size_t)row * DIM)
                                     : (pred + (size_t)(row - NROWS) * DIM);
    const float4 v0 = *(const float4*)(src + l * 8);
    const float4 v1 = *(const float4*)(src + l * 8 + 4);
    float h[8] = {v0.x, v0.y, v0.z, v0.w, v1.x, v1.y, v1.z, v1.w};

    float nrm = 0.f;  // exact f32 norm of the ORIGINAL row (fallback uses it)
#pragma unroll
    for (int j = 0; j < 8; ++j) nrm += h[j] * h[j];
#pragma unroll
    for (int off = 32; off; off >>= 1) nrm += __shfl_xor(nrm, off);
    if (l == 0) xnorm[row] = nrm;

#define BFLY(a, b) { float t = h[a]; h[a] = t + h[b]; h[b] = t - h[b]; }
    BFLY(0, 1) BFLY(2, 3) BFLY(4, 5) BFLY(6, 7)
    BFLY(0, 2) BFLY(1, 3) BFLY(4, 6) BFLY(5, 7)
    BFLY(0, 4) BFLY(1, 5) BFLY(2, 6) BFLY(3, 7)
#undef BFLY
#pragma unroll
    for (int m = 1; m <= 32; m <<= 1) {
#pragma unroll
        for (int j = 0; j < 8; ++j) {
            float p = __shfl_xor(h[j], m);
            h[j] = (l & m) ? (p - h[j]) : (h[j] + p);
        }
    }
    float s = 0.f;
    uint32_t pk[4];
#pragma unroll
    for (int jj = 0; jj < 4; ++jj) {
        uint32_t b0 = __float_as_uint(h[2 * jj] * 0.04419417382f);
        uint32_t b1 = __float_as_uint(h[2 * jj + 1] * 0.04419417382f);
        uint32_t r0 = (b0 + 0x7fffu + ((b0 >> 16) & 1u)) >> 16;
        uint32_t r1 = (b1 + 0x7fffu + ((b1 >> 16) & 1u)) >> 16;
        pk[jj] = r0 | (r1 << 16);
        float fb0 = __uint_as_float(r0 << 16);
        float fb1 = __uint_as_float(r1 << 16);
        s += fb0 * fb0 + fb1 * fb1;
    }
    if (l < 16) {
        const size_t unit = (size_t)(row >> 4) * 256 + (l >> 2) * 64 + (l & 3) * 16 + (row & 15);
        *((uint4*)Qf + unit) = make_uint4(pk[0], pk[1], pk[2], pk[3]);
    }
    s = (l < 16) ? s : 0.f;
#pragma unroll
    for (int off = 32; off; off >>= 1) s += __shfl_xor(s, off);
    if (l == 0) pnorm[row] = s;
}

// ---------------- kernel 2: 2-tile register-MFMA filter, 4 blocks/CU --------------
// r14 body with GRID 520->1040 (2 tiles/block): resident occupancy 2->4 blocks/CU
// (4 waves/SIMD) to interleave the ~120cyc/chunk L2-latency stalls; cross-tile
// prefetch retained (next tile's chunk-0 loads into freed even regs ahead of the
// epilogue). No LDS, no barriers.
__global__ __launch_bounds__(256) void mmd_filter_kernel(const u16* __restrict__ Qf,
                                                         const float* __restrict__ pnorm,
                                                         const float* __restrict__ lbl,
                                                         const float* __restrict__ pred,
                                                         const float* __restrict__ xnorm,
                                                         float* __restrict__ partials) {
    __shared__ float red[4];

    const int bid0 = (int)blockIdx.x;
    const int phys = (bid0 & 7) * (GRID3 / 8) + (bid0 >> 3);  // XCD-contiguous
    const int tid = threadIdx.x;
    const int wv = tid >> 6;
    const int l = tid & 63;
    const int wm = wv >> 1, wn = wv & 1;
    const int rl = l & 15;

    // decode first triangle index (block handles ids 2*phys, 2*phys+1)
    int bm = 0, rem = phys * 2;
    while (rem >= NTILES - bm) { rem -= NTILES - bm; ++bm; }

    auto baseof = [&](int rowblk) {
        return (const char*)Qf + (size_t)(rowblk >> 4) * 4096 + (size_t)l * 16;
    };

    f32x4 acc[4][4];
#pragma unroll
    for (int m = 0; m < 4; ++m)
#pragma unroll
        for (int n = 0; n < 4; ++n) acc[m][n] = (f32x4){0.f, 0.f, 0.f, 0.f};

    bf16x8 aE[4], bE[4], aO[4], bO[4];
    const char* bA = baseof(bm * 128 + wm * 64);
    const char* bB = baseof((bm + rem) * 128 + wn * 64);

#define LDX(a, b, kc, pA, pB)                                    \
    {                                                            \
        _Pragma("unroll") for (int m = 0; m < 4; ++m) {          \
            a[m] = *(const bf16x8*)((pA) + m * 4096 + (kc) * 1024); \
            b[m] = *(const bf16x8*)((pB) + m * 4096 + (kc) * 1024); \
        }                                                        \
    }
#define MMX(a, b)                                                \
    {                                                            \
        _Pragma("unroll") for (int m = 0; m < 4; ++m)            \
            _Pragma("unroll") for (int n = 0; n < 4; ++n)        \
                acc[m][n] = __builtin_amdgcn_mfma_f32_16x16x32_bf16(a[m], b[n], acc[m][n], 0, 0, 0); \
    }

    LDX(aE, bE, 0, bA, bB);
    float grand = 0.f;

#pragma unroll 1
    for (int k = 0; k < 2; ++k) {
        const int bn = bm + rem;
        const int rowA = bm * 128 + wm * 64;
        const int rowB = bn * 128 + wn * 64;

        LDX(aO, bO, 1, bA, bB); MMX(aE, bE);
        LDX(aE, bE, 2, bA, bB); MMX(aO, bO);
        LDX(aO, bO, 3, bA, bB); MMX(aE, bE);

        // advance to next tile; prefetch its chunk 0 into the freed even regs
        int bm2 = bm, rem2 = rem + 1;
        if (rem2 >= NTILES - bm2) { rem2 = 0; ++bm2; }
        if (k < 1) {
            bA = baseof(bm2 * 128 + wm * 64);
            bB = baseof((bm2 + rem2) * 128 + wn * 64);
            LDX(aE, bE, 0, bA, bB);
        }
        MMX(aO, bO);

        // ---- epilogue (register-only; certify-skip + rare exact fallback) ----
        float pj[4];
        float4 piv[4];
#pragma unroll
        for (int n = 0; n < 4; ++n) pj[n] = pnorm[rowB + n * 16 + rl];
#pragma unroll
        for (int m = 0; m < 4; ++m)
            piv[m] = *(const float4*)(pnorm + rowA + m * 16 + (l >> 4) * 4);

        float tmin = 1e30f;  // min fragment distance (i==j excluded)
#pragma unroll
        for (int m = 0; m < 4; ++m)
#pragma unroll
            for (int n = 0; n < 4; ++n) {
                const int i0 = rowA + m * 16 + (l >> 4) * 4;
                const int j = rowB + n * 16 + rl;
                const int delta = j - i0;
                float d0 = (piv[m].x + pj[n]) - 2.f * acc[m][n][0];
                float d1 = (piv[m].y + pj[n]) - 2.f * acc[m][n][1];
                float d2 = (piv[m].z + pj[n]) - 2.f * acc[m][n][2];
                float d3 = (piv[m].w + pj[n]) - 2.f * acc[m][n][3];
                d0 = (delta == 0) ? 1e30f : d0;
                d1 = (delta == 1) ? 1e30f : d1;
                d2 = (delta == 2) ? 1e30f : d2;
                d3 = (delta == 3) ? 1e30f : d3;
                tmin = fminf(tmin, fminf(fminf(d0, d1), fminf(d2, d3)));
            }

        if (__ballot(tmin < THR)) {  // ≈never taken (certified); wave-uniform
            float local = 0.f;
#pragma unroll
            for (int m = 0; m < 4; ++m)
#pragma unroll
                for (int n = 0; n < 4; ++n) {
                    float d[4];
                    d[0] = (piv[m].x + pj[n]) - 2.f * acc[m][n][0];
                    d[1] = (piv[m].y + pj[n]) - 2.f * acc[m][n][1];
                    d[2] = (piv[m].z + pj[n]) - 2.f * acc[m][n][2];
                    d[3] = (piv[m].w + pj[n]) - 2.f * acc[m][n][3];
                    const int i0 = rowA + m * 16 + (l >> 4) * 4;
                    const int j = rowB + n * 16 + rl;
#pragma unroll
                    for (int r = 0; r < 4; ++r) {
                        unsigned long long bal = __ballot((d[r] < THR) && (i0 + r != j));
                        while (bal) {  // wave-cooperative exact f32 term
                            const int src = __ffsll((long long)bal) - 1;
                            bal &= bal - 1;
                            const int ii = __shfl(i0 + r, src);
                            const int jj = __shfl(j, src);
                            const float* ri = (ii < NROWS) ? lbl + (size_t)ii * DIM
                                                           : pred + (size_t)(ii - NROWS) * DIM;
                            const float* rj = (jj < NROWS) ? lbl + (size_t)jj * DIM
                                                           : pred + (size_t)(jj - NROWS) * DIM;
                            const float4 a0 = *(const float4*)(ri + l * 8);
                            const float4 a1 = *(const float4*)(ri + l * 8 + 4);
                            const float4 c0 = *(const float4*)(rj + l * 8);
                            const float4 c1 = *(const float4*)(rj + l * 8 + 4);
                            float p = a0.x * c0.x + a0.y * c0.y + a0.z * c0.z + a0.w * c0.w +
                                      a1.x * c1.x + a1.y * c1.y + a1.z * c1.z + a1.w * c1.w;
#pragma unroll
                            for (int off = 32; off; off >>= 1) p += __shfl_xor(p, off);
                            if (l == src) {
                                float dt = xnorm[ii] + xnorm[jj] - 2.f * p;
                                local += exp2f(-0.72134752f * dt);
                            }
                        }
                    }
                }
            const float sgn = ((bm < 32) == (bn < 32)) ? 1.f : -1.f;
            grand += local * sgn * ((bm == bn) ? 1.f : 2.f);
        }
#pragma unroll
        for (int m = 0; m < 4; ++m)
#pragma unroll
            for (int n = 0; n < 4; ++n) acc[m][n] = (f32x4){0.f, 0.f, 0.f, 0.f};
        bm = bm2; rem = rem2;
    }
#undef LDX
#undef MMX

    // ---- block reduce ----
#pragma unroll
    for (int off = 32; off; off >>= 1) grand += __shfl_xor(grand, off);
    if (l == 0) red[wv] = grand;
    __syncthreads();
    if (tid == 0) partials[phys] = red[0] + red[1] + red[2] + red[3];
}

// ---------------- kernel 3: deterministic final reduce ---------------------------
__global__ __launch_bounds__(256) void reduce_kernel(const float* __restrict__ partials,
                                                     float* __restrict__ out, int n) {
    __shared__ float red[4];
    float s = 0.f;
    for (int i = threadIdx.x; i < n; i += 256) s += partials[i];
#pragma unroll
    for (int off = 32; off; off >>= 1) s += __shfl_xor(s, off);
    if ((threadIdx.x & 63) == 0) red[threadIdx.x >> 6] = s;
    __syncthreads();
    if (threadIdx.x == 0)  // + 8192 = the Z-diagonal (exp(0)=1, sign +1, exact)
        out[0] = (red[0] + red[1] + red[2] + red[3] + 8192.f) * (1.f / 16777216.f);
}

extern "C" void kernel_launch(void* const* d_in, const int* in_sizes, int n_in,
                              void* d_out, int out_size, void* d_ws, size_t ws_size,
                              hipStream_t stream) {
    const float* lbl = (const float*)d_in[0];
    const float* pred = (const float*)d_in[1];
    u16* Qf = (u16*)d_ws;                                             // 2 MiB
    float* xnorm = (float*)((char*)d_ws + (size_t)ZROWS * DIMP * 2);  // 32 KiB
    float* pnorm = xnorm + ZROWS;                                     // 32 KiB
    float* partials = pnorm + ZROWS;                                  // 4.2 KiB

    prep_kernel<<<ZROWS / 4, 256, 0, stream>>>(lbl, pred, Qf, xnorm, pnorm);
    mmd_filter_kernel<<<GRID3, 256, 0, stream>>>(Qf, pnorm, lbl, pred, xnorm, partials);
    reduce_kernel<<<1, 256, 0, stream>>>(partials, (float*)d_out, GRID3);
}